// Round 1
// baseline (1420.807 us; speedup 1.0000x reference)
//
#include <hip/hip_runtime.h>

// SIGN convolution: h = x @ W + b ; out = segment_sum(adj_vals[:,None] * h[edge_cols], edge_rows)
// x [N,256] f32, W [256,64] f32, b [64] f32, E=1.6M edges.

constexpr int KDIM = 256;   // n_in
constexpr int MOUT = 64;    // n_out
constexpr int TILE_R = 64;  // rows per block
constexpr int KC = 64;      // K chunk staged in LDS

// ---------------- Phase 1: dense GEMM h = x@W + b (fp32, VALU) ----------------
__global__ __launch_bounds__(256)
void gemm_xw_b(const float* __restrict__ x, const float* __restrict__ W,
               const float* __restrict__ bvec, float* __restrict__ h, int N) {
  // xs padded to 68 floats/row: staging writes are float4 (conflict-free),
  // inner-loop reads are scalar broadcast across the 16 tx lanes, 2-way max.
  __shared__ float xs[TILE_R][KC + 4];  // 17408 B
  __shared__ float ws[KC][MOUT];        // 16384 B

  const int tid = threadIdx.x;
  const int tx = tid & 15;   // col group: cols tx*4 .. tx*4+3
  const int ty = tid >> 4;   // row group: rows ty*4 .. ty*4+3
  const int row0 = blockIdx.x * TILE_R;

  float acc[4][4];
#pragma unroll
  for (int r = 0; r < 4; ++r)
#pragma unroll
    for (int c = 0; c < 4; ++c) acc[r][c] = 0.f;

  for (int kc = 0; kc < KDIM; kc += KC) {
    // stage x tile: 64 rows x 64 k = 1024 float4, 4 per thread
#pragma unroll
    for (int i = 0; i < 4; ++i) {
      int flat = tid + i * 256;        // float4 index 0..1023
      int r = flat >> 4;               // tile row (16 float4 per row)
      int k4 = flat & 15;
      int grow = row0 + r;
      int grc = grow < N ? grow : N - 1;  // clamp; stores are guarded
      float4 v = *reinterpret_cast<const float4*>(&x[(size_t)grc * KDIM + kc + k4 * 4]);
      *reinterpret_cast<float4*>(&xs[r][k4 * 4]) = v;
    }
    // stage W tile: 64 k x 64 cols, row-major, direct float4
#pragma unroll
    for (int i = 0; i < 4; ++i) {
      int flat = tid + i * 256;
      int k = flat >> 4;
      int c4 = flat & 15;
      float4 v = *reinterpret_cast<const float4*>(&W[(size_t)(kc + k) * MOUT + c4 * 4]);
      *reinterpret_cast<float4*>(&ws[k][c4 * 4]) = v;
    }
    __syncthreads();

#pragma unroll 16
    for (int k = 0; k < KC; ++k) {
      float a0 = xs[ty * 4 + 0][k];
      float a1 = xs[ty * 4 + 1][k];
      float a2 = xs[ty * 4 + 2][k];
      float a3 = xs[ty * 4 + 3][k];
      float4 bq = *reinterpret_cast<const float4*>(&ws[k][tx * 4]);
      acc[0][0] += a0 * bq.x; acc[0][1] += a0 * bq.y; acc[0][2] += a0 * bq.z; acc[0][3] += a0 * bq.w;
      acc[1][0] += a1 * bq.x; acc[1][1] += a1 * bq.y; acc[1][2] += a1 * bq.z; acc[1][3] += a1 * bq.w;
      acc[2][0] += a2 * bq.x; acc[2][1] += a2 * bq.y; acc[2][2] += a2 * bq.z; acc[2][3] += a2 * bq.w;
      acc[3][0] += a3 * bq.x; acc[3][1] += a3 * bq.y; acc[3][2] += a3 * bq.z; acc[3][3] += a3 * bq.w;
    }
    __syncthreads();
  }

  float4 bb = *reinterpret_cast<const float4*>(&bvec[tx * 4]);
#pragma unroll
  for (int r = 0; r < 4; ++r) {
    int grow = row0 + ty * 4 + r;
    if (grow < N) {
      float4 o;
      o.x = acc[r][0] + bb.x;
      o.y = acc[r][1] + bb.y;
      o.z = acc[r][2] + bb.z;
      o.w = acc[r][3] + bb.w;
      *reinterpret_cast<float4*>(&h[(size_t)grow * MOUT + tx * 4]) = o;
    }
  }
}

// ---------------- Phase 2: edge scatter with f32 atomics ----------------
// 16 lanes per edge; each lane handles 4 consecutive floats of the 64-wide row.
__global__ __launch_bounds__(256)
void scatter_edges(const float* __restrict__ h, const float* __restrict__ vals,
                   const int* __restrict__ rows, const int* __restrict__ cols,
                   float* __restrict__ out, int E) {
  long long idx = (long long)blockIdx.x * blockDim.x + threadIdx.x;
  int e = (int)(idx >> 4);
  int part = (int)(idx & 15);
  if (e >= E) return;
  int r = rows[e];
  int c = cols[e];
  float v = vals[e];
  float4 hv = *reinterpret_cast<const float4*>(&h[(size_t)c * MOUT + part * 4]);
  float* op = &out[(size_t)r * MOUT + part * 4];
  atomicAdd(op + 0, v * hv.x);
  atomicAdd(op + 1, v * hv.y);
  atomicAdd(op + 2, v * hv.z);
  atomicAdd(op + 3, v * hv.w);
}

extern "C" void kernel_launch(void* const* d_in, const int* in_sizes, int n_in,
                              void* d_out, int out_size, void* d_ws, size_t ws_size,
                              hipStream_t stream) {
  const float* x    = (const float*)d_in[0];
  const float* W    = (const float*)d_in[1];
  const float* bvec = (const float*)d_in[2];
  const float* vals = (const float*)d_in[3];
  const int* erows  = (const int*)d_in[4];
  const int* ecols  = (const int*)d_in[5];
  float* out = (float*)d_out;

  const int N = in_sizes[0] / KDIM;   // 100000
  const int E = in_sizes[3];          // 1600000

  float* h = (float*)d_ws;            // N*64 floats = 25.6 MB scratch

  // zero output (harness poisons it; scatter accumulates)
  hipMemsetAsync(d_out, 0, (size_t)out_size * sizeof(float), stream);

  dim3 gblk(256);
  dim3 ggrid((N + TILE_R - 1) / TILE_R);
  gemm_xw_b<<<ggrid, gblk, 0, stream>>>(x, W, bvec, h, N);

  long long work = (long long)E * 16;
  dim3 sgrid((unsigned)((work + 255) / 256));
  scatter_edges<<<sgrid, gblk, 0, stream>>>(h, vals, erows, ecols, out, E);
}

// Round 2
// 307.337 us; speedup vs baseline: 4.6230x; 4.6230x over previous
//
#include <hip/hip_runtime.h>

// SIGN convolution: h = x @ W + b ; out = segment_sum(adj_vals[:,None] * h[edge_cols], edge_rows)
// x [N,256] f32, W [256,64] f32, b [64] f32, E=1.6M edges.
//
// Round 2: replace 102.4M f32 atomicAdds (atomic-throughput bound, 1350us) with
// on-device CSR build (hist + scan + reorder) and a pull-mode one-wave-per-row reduce.

constexpr int KDIM = 256;   // n_in
constexpr int MOUT = 64;    // n_out
constexpr int TILE_R = 64;  // rows per block
constexpr int KC = 64;      // K chunk staged in LDS

// ---------------- Phase 1: dense GEMM h = x@W + b (fp32, VALU) ----------------
__global__ __launch_bounds__(256)
void gemm_xw_b(const float* __restrict__ x, const float* __restrict__ W,
               const float* __restrict__ bvec, float* __restrict__ h, int N) {
  __shared__ float xs[TILE_R][KC + 4];  // 17408 B (pad: scalar reads broadcast)
  __shared__ float ws[KC][MOUT];        // 16384 B

  const int tid = threadIdx.x;
  const int tx = tid & 15;   // col group: cols tx*4 .. tx*4+3
  const int ty = tid >> 4;   // row group: rows ty*4 .. ty*4+3
  const int row0 = blockIdx.x * TILE_R;

  float acc[4][4];
#pragma unroll
  for (int r = 0; r < 4; ++r)
#pragma unroll
    for (int c = 0; c < 4; ++c) acc[r][c] = 0.f;

  for (int kc = 0; kc < KDIM; kc += KC) {
#pragma unroll
    for (int i = 0; i < 4; ++i) {
      int flat = tid + i * 256;        // float4 index 0..1023
      int r = flat >> 4;
      int k4 = flat & 15;
      int grow = row0 + r;
      int grc = grow < N ? grow : N - 1;  // clamp; stores are guarded
      float4 v = *reinterpret_cast<const float4*>(&x[(size_t)grc * KDIM + kc + k4 * 4]);
      *reinterpret_cast<float4*>(&xs[r][k4 * 4]) = v;
    }
#pragma unroll
    for (int i = 0; i < 4; ++i) {
      int flat = tid + i * 256;
      int k = flat >> 4;
      int c4 = flat & 15;
      float4 v = *reinterpret_cast<const float4*>(&W[(size_t)(kc + k) * MOUT + c4 * 4]);
      *reinterpret_cast<float4*>(&ws[k][c4 * 4]) = v;
    }
    __syncthreads();

#pragma unroll 16
    for (int k = 0; k < KC; ++k) {
      float a0 = xs[ty * 4 + 0][k];
      float a1 = xs[ty * 4 + 1][k];
      float a2 = xs[ty * 4 + 2][k];
      float a3 = xs[ty * 4 + 3][k];
      float4 bq = *reinterpret_cast<const float4*>(&ws[k][tx * 4]);
      acc[0][0] += a0 * bq.x; acc[0][1] += a0 * bq.y; acc[0][2] += a0 * bq.z; acc[0][3] += a0 * bq.w;
      acc[1][0] += a1 * bq.x; acc[1][1] += a1 * bq.y; acc[1][2] += a1 * bq.z; acc[1][3] += a1 * bq.w;
      acc[2][0] += a2 * bq.x; acc[2][1] += a2 * bq.y; acc[2][2] += a2 * bq.z; acc[2][3] += a2 * bq.w;
      acc[3][0] += a3 * bq.x; acc[3][1] += a3 * bq.y; acc[3][2] += a3 * bq.z; acc[3][3] += a3 * bq.w;
    }
    __syncthreads();
  }

  float4 bb = *reinterpret_cast<const float4*>(&bvec[tx * 4]);
#pragma unroll
  for (int r = 0; r < 4; ++r) {
    int grow = row0 + ty * 4 + r;
    if (grow < N) {
      float4 o;
      o.x = acc[r][0] + bb.x;
      o.y = acc[r][1] + bb.y;
      o.z = acc[r][2] + bb.z;
      o.w = acc[r][3] + bb.w;
      *reinterpret_cast<float4*>(&h[(size_t)grow * MOUT + tx * 4]) = o;
    }
  }
}

// ---------------- CSR build ----------------
__global__ __launch_bounds__(256)
void hist_rows(const int* __restrict__ rows, int* __restrict__ cnt, int E) {
  int e = blockIdx.x * 256 + threadIdx.x;
  if (e < E) atomicAdd(&cnt[rows[e]], 1);
}

// Per-block exclusive scan of cnt -> row_ptr (partial), block totals out.
__global__ __launch_bounds__(1024)
void scan_blocks(const int* __restrict__ cnt, int* __restrict__ row_ptr,
                 int* __restrict__ blockSums, int N) {
  __shared__ int buf[1024];
  int t = threadIdx.x;
  int i = blockIdx.x * 1024 + t;
  int x = (i < N) ? cnt[i] : 0;
  buf[t] = x;
  __syncthreads();
#pragma unroll
  for (int off = 1; off < 1024; off <<= 1) {
    int v = (t >= off) ? buf[t - off] : 0;
    __syncthreads();
    buf[t] += v;
    __syncthreads();
  }
  int incl = buf[t];
  if (i < N) row_ptr[i] = incl - x;  // exclusive, partial (needs block offset)
  if (t == 1023) blockSums[blockIdx.x] = incl;
}

// Exclusive scan of block totals (NB <= 1024) -> blockOffs.
__global__ __launch_bounds__(1024)
void scan_totals(const int* __restrict__ blockSums, int* __restrict__ blockOffs, int NB) {
  __shared__ int buf[1024];
  int t = threadIdx.x;
  int x = (t < NB) ? blockSums[t] : 0;
  buf[t] = x;
  __syncthreads();
#pragma unroll
  for (int off = 1; off < 1024; off <<= 1) {
    int v = (t >= off) ? buf[t - off] : 0;
    __syncthreads();
    buf[t] += v;
    __syncthreads();
  }
  if (t < NB) blockOffs[t] = buf[t] - x;
}

// Add block offsets; copy finalized row_ptr into cursor; write row_ptr[N]=E.
__global__ __launch_bounds__(1024)
void add_offsets(int* __restrict__ row_ptr, int* __restrict__ cursor,
                 const int* __restrict__ blockOffs, int N, int E) {
  int i = blockIdx.x * 1024 + threadIdx.x;
  if (i < N) {
    int v = row_ptr[i] + blockOffs[blockIdx.x];
    row_ptr[i] = v;
    cursor[i] = v;
  }
  if (i == 0) row_ptr[N] = E;
}

// Scatter edges into row-sorted order as (col, val_bits) pairs.
__global__ __launch_bounds__(256)
void reorder_edges(const int* __restrict__ rows, const int* __restrict__ cols,
                   const float* __restrict__ vals, int* __restrict__ cursor,
                   int2* __restrict__ sorted, int E) {
  int e = blockIdx.x * 256 + threadIdx.x;
  if (e >= E) return;
  int r = rows[e];
  int pos = atomicAdd(&cursor[r], 1);
  sorted[pos] = make_int2(cols[e], __float_as_int(vals[e]));
}

// ---------------- Pull-mode reduce: one wave per output row ----------------
// lane = sub*16 + part; 16 lanes (part) cover the 64-wide row as float4;
// 4 edge-slots (sub) process edges in parallel; shfl_xor folds the slots.
__global__ __launch_bounds__(256)
void reduce_rows(const float* __restrict__ h, const int2* __restrict__ sorted,
                 const int* __restrict__ row_ptr, float* __restrict__ out, int N) {
  int row = (blockIdx.x * 256 + threadIdx.x) >> 6;
  if (row >= N) return;
  int lane = threadIdx.x & 63;
  int sub = lane >> 4;
  int part = lane & 15;
  int s = row_ptr[row];
  int e = row_ptr[row + 1];
  float4 acc = make_float4(0.f, 0.f, 0.f, 0.f);
  for (int j = s + sub; j < e; j += 4) {
    int2 p = sorted[j];
    float v = __int_as_float(p.y);
    float4 hv = *reinterpret_cast<const float4*>(&h[(size_t)p.x * MOUT + part * 4]);
    acc.x += v * hv.x;
    acc.y += v * hv.y;
    acc.z += v * hv.z;
    acc.w += v * hv.w;
  }
#pragma unroll
  for (int m = 16; m <= 32; m <<= 1) {
    acc.x += __shfl_xor(acc.x, m, 64);
    acc.y += __shfl_xor(acc.y, m, 64);
    acc.z += __shfl_xor(acc.z, m, 64);
    acc.w += __shfl_xor(acc.w, m, 64);
  }
  if (sub == 0)
    *reinterpret_cast<float4*>(&out[(size_t)row * MOUT + part * 4]) = acc;
}

// ---------------- Fallback: f32-atomic scatter (if ws too small) ----------------
__global__ __launch_bounds__(256)
void scatter_edges(const float* __restrict__ h, const float* __restrict__ vals,
                   const int* __restrict__ rows, const int* __restrict__ cols,
                   float* __restrict__ out, int E) {
  long long idx = (long long)blockIdx.x * blockDim.x + threadIdx.x;
  int e = (int)(idx >> 4);
  int part = (int)(idx & 15);
  if (e >= E) return;
  int r = rows[e];
  int c = cols[e];
  float v = vals[e];
  float4 hv = *reinterpret_cast<const float4*>(&h[(size_t)c * MOUT + part * 4]);
  float* op = &out[(size_t)r * MOUT + part * 4];
  atomicAdd(op + 0, v * hv.x);
  atomicAdd(op + 1, v * hv.y);
  atomicAdd(op + 2, v * hv.z);
  atomicAdd(op + 3, v * hv.w);
}

static inline size_t align256(size_t x) { return (x + 255) & ~(size_t)255; }

extern "C" void kernel_launch(void* const* d_in, const int* in_sizes, int n_in,
                              void* d_out, int out_size, void* d_ws, size_t ws_size,
                              hipStream_t stream) {
  const float* x    = (const float*)d_in[0];
  const float* W    = (const float*)d_in[1];
  const float* bvec = (const float*)d_in[2];
  const float* vals = (const float*)d_in[3];
  const int* erows  = (const int*)d_in[4];
  const int* ecols  = (const int*)d_in[5];
  float* out = (float*)d_out;

  const int N = in_sizes[0] / KDIM;   // 100000
  const int E = in_sizes[3];          // 1600000
  const int NB = (N + 1023) / 1024;   // scan blocks (98)

  // workspace layout
  char* ws = (char*)d_ws;
  size_t off_h  = 0;
  size_t off_rp = align256(off_h + (size_t)N * MOUT * sizeof(float));
  size_t off_cu = align256(off_rp + (size_t)(N + 1) * sizeof(int));
  size_t off_bs = align256(off_cu + (size_t)N * sizeof(int));
  size_t off_bo = align256(off_bs + 1024 * sizeof(int));
  size_t off_sp = align256(off_bo + 1024 * sizeof(int));
  size_t need   = off_sp + (size_t)E * sizeof(int2);

  float* h = (float*)(ws + off_h);

  dim3 blk256(256);
  dim3 ggrid((N + TILE_R - 1) / TILE_R);
  gemm_xw_b<<<ggrid, blk256, 0, stream>>>(x, W, bvec, h, N);

  if (ws_size >= need && NB <= 1024) {
    int* row_ptr   = (int*)(ws + off_rp);
    int* cursor    = (int*)(ws + off_cu);
    int* blockSums = (int*)(ws + off_bs);
    int* blockOffs = (int*)(ws + off_bo);
    int2* sorted   = (int2*)(ws + off_sp);

    hipMemsetAsync(cursor, 0, (size_t)N * sizeof(int), stream);  // counts
    hist_rows<<<dim3((E + 255) / 256), blk256, 0, stream>>>(erows, cursor, E);
    scan_blocks<<<dim3(NB), dim3(1024), 0, stream>>>(cursor, row_ptr, blockSums, N);
    scan_totals<<<dim3(1), dim3(1024), 0, stream>>>(blockSums, blockOffs, NB);
    add_offsets<<<dim3(NB), dim3(1024), 0, stream>>>(row_ptr, cursor, blockOffs, N, E);
    reorder_edges<<<dim3((E + 255) / 256), blk256, 0, stream>>>(erows, ecols, vals, cursor, sorted, E);
    reduce_rows<<<dim3((N * 64 + 255) / 256), blk256, 0, stream>>>(h, sorted, row_ptr, out, N);
  } else {
    hipMemsetAsync(d_out, 0, (size_t)out_size * sizeof(float), stream);
    long long work = (long long)E * 16;
    scatter_edges<<<dim3((unsigned)((work + 255) / 256)), blk256, 0, stream>>>(h, vals, erows, ecols, out, E);
  }
}